// Round 1
// baseline (367.719 us; speedup 1.0000x reference)
//
#include <hip/hip_runtime.h>
#include <hip/hip_bf16.h>
#include <stdint.h>

#define NB 4096
#define NC 100
#define NROWS (NB*NC)   // 409600
#define LH 200
#define LW 50

typedef short v8s __attribute__((ext_vector_type(8)));
typedef float v4f __attribute__((ext_vector_type(4)));

__device__ __forceinline__ v4f mfma16(v8s a, v8s b, v4f c) {
  return __builtin_amdgcn_mfma_f32_16x16x32_bf16(a, b, c, 0, 0, 0);
}

// packed f32x2 -> bf16x2 (lo = first arg), RNE
__device__ __forceinline__ uint32_t pkbf(float lo, float hi) {
  uint32_t r;
  asm("v_cvt_pk_bf16_f32 %0, %1, %2" : "=v"(r) : "v"(lo), "v"(hi));
  return r;
}

__device__ __forceinline__ uint16_t bf16r(float f) {
  uint32_t u = __builtin_bit_cast(uint32_t, f);
  u = (u + 0x7fffu + ((u >> 16) & 1u)) >> 16;
  return (uint16_t)u;
}

__device__ __forceinline__ float bf2f(short s) {
  return __builtin_bit_cast(float, (uint32_t)((uint16_t)s) << 16);
}

// ---------------- kernel 1: user vector (hist/wish mean pool) ----------------
__global__ void k_user(const int* __restrict__ hist, const int* __restrict__ wish,
                       const float* __restrict__ Eh, const float* __restrict__ Ew,
                       float* __restrict__ uv) {
  int t = threadIdx.x;
  int d = t & 31;
  int r = (blockIdx.x << 3) + (t >> 5);   // 8 rows per 256-thread block
  const int* hr = hist + r * LH;
  float s = 0.f;
  #pragma unroll 8
  for (int j = 0; j < LH; ++j) s += Eh[hr[j] * 32 + d];
  float su = s * (1.0f / LH);
  const int* wr = wish + r * LW;
  s = 0.f;
  #pragma unroll 5
  for (int j = 0; j < LW; ++j) s += Ew[wr[j] * 32 + d];
  uv[r * 32 + d] = su + s * (1.0f / LW);
}

// ---------------- kernel 2: fused item pipeline ----------------
// LDS map (bytes). Rows >=128B use swz byte^=((row&7)<<4); 64B rows use (row&3)<<4.
#define SM_WT0T 0        // [256 n][64 k] bf16 = 32768   (k: 0..31 natural(u), 32..63 PERM32)
#define SM_WT1T 32768    // [128 n][256 k] bf16 = 65536  (k: PERM32)
#define SM_WT2T 98304    // [64 n][128 k] bf16 = 16384   (k: PERM32)
#define SM_WB1T 114688   // [32 n][32 k] bf16 = 2048     (k natural)
#define SM_BIAS 116736   // bb1[32] bt0[256] bt1[128] bt2[64] f32 = 1920
#define SM_ACT3 118656   // [64][64] bf16 = 8192 (aliases H + first half of X)
#define SM_H    118656   // [64][32] bf16 = 4096
#define SM_X    122752   // [64][64] bf16 = 8192 (cols 0..31 u natural, 32..63 paired)
#define SM_ACT1 130944   // [64][128] bf16 = 16384 (one 128-col chunk, paired)
#define SM_ACT2 147328   // [64][128] bf16 = 16384 (paired)
#define SM_BYTES 163712
#define PERM32(s) (((s) & ~31) + (((s) & 31) >> 1) + (((s) & 1) << 4))

__global__ __launch_bounds__(256, 1)
void k_fused(const int* __restrict__ cand, const int* __restrict__ auth,
             const int* __restrict__ lang, const int* __restrict__ tags,
             const float* __restrict__ dense,
             const float* __restrict__ Ec, const float* __restrict__ Ea,
             const float* __restrict__ El, const float* __restrict__ Et,
             const float* __restrict__ Wb0, const float* __restrict__ bb0,
             const float* __restrict__ Wb1, const float* __restrict__ bb1,
             const float* __restrict__ Wt0, const float* __restrict__ bt0,
             const float* __restrict__ Wt1, const float* __restrict__ bt1,
             const float* __restrict__ Wt2, const float* __restrict__ bt2,
             const float* __restrict__ Wt3, const float* __restrict__ bt3,
             const float* __restrict__ uvec, float* __restrict__ out,
             int tiles_per_blk) {
  extern __shared__ char sm[];
  const int t = threadIdx.x;
  const int l = t & 63, wv = t >> 6;
  const int lr = l & 15, lg = l >> 4;
  const int q = t & 3, rowl = t >> 2;

  // ---- stage weights (transposed + permuted + swizzled bf16) ----
  for (int i = t; i < 256 * 64; i += 256) {          // Wt0T
    int n = i & 255, ks = i >> 8;
    int ok = (ks < 32) ? ks : PERM32(ks);
    *(uint16_t*)(sm + SM_WT0T + n * 128 + ((ks * 2) ^ ((n & 7) << 4))) = bf16r(Wt0[ok * 256 + n]);
  }
  for (int i = t; i < 128 * 256; i += 256) {         // Wt1T
    int n = i & 127, ks = i >> 7;
    int ok = PERM32(ks);
    *(uint16_t*)(sm + SM_WT1T + n * 512 + ((ks * 2) ^ ((n & 7) << 4))) = bf16r(Wt1[ok * 128 + n]);
  }
  for (int i = t; i < 64 * 128; i += 256) {          // Wt2T
    int n = i & 63, ks = i >> 6;
    int ok = PERM32(ks);
    *(uint16_t*)(sm + SM_WT2T + n * 256 + ((ks * 2) ^ ((n & 7) << 4))) = bf16r(Wt2[ok * 64 + n]);
  }
  for (int i = t; i < 32 * 32; i += 256) {           // Wb1T
    int n = i & 31, ks = i >> 5;
    *(uint16_t*)(sm + SM_WB1T + n * 64 + ((ks * 2) ^ ((n & 3) << 4))) = bf16r(Wb1[ks * 32 + n]);
  }
  float* bb1l = (float*)(sm + SM_BIAS);
  float* bt0l = bb1l + 32;
  float* bt1l = bt0l + 256;
  float* bt2l = bt1l + 128;
  if (t < 32)  bb1l[t] = bb1[t];
  bt0l[t] = bt0[t];
  if (t < 128) bt1l[t] = bt1[t];
  if (t < 64)  bt2l[t] = bt2[t];

  // hoisted per-thread constants
  float wb0r[3][8], bb0r[8], wt3r[16];
  #pragma unroll
  for (int j = 0; j < 8; ++j) {
    bb0r[j] = bb0[q * 8 + j];
    #pragma unroll
    for (int f = 0; f < 3; ++f) wb0r[f][j] = Wb0[f * 32 + q * 8 + j];
  }
  #pragma unroll
  for (int j = 0; j < 16; ++j) wt3r[j] = Wt3[q * 16 + j];
  const float bt3v = bt3[0];

  const int tile0 = blockIdx.x * tiles_per_blk;
  for (int tt = 0; tt < tiles_per_blk; ++tt) {
    const int r0 = (tile0 + tt) << 6;
    __syncthreads();   // protects act3/X/h reuse across tiles (and staging, tile 0)

    // ---- P0: X u-part + bottom-MLP layer0 (h) : thread = (row rowl, col-slice q) ----
    {
      int r = r0 + rowl;
      int b = r / 100;
      const float* up = uvec + b * 32 + q * 8;
      int xrb = SM_X + rowl * 128;
      int sw  = (rowl & 7) << 4;
      #pragma unroll
      for (int u2 = 0; u2 < 4; ++u2)
        *(uint32_t*)(sm + xrb + ((q * 16 + u2 * 4) ^ sw)) = pkbf(up[u2 * 2], up[u2 * 2 + 1]);
      float d0 = dense[r * 3 + 0], d1 = dense[r * 3 + 1], d2 = dense[r * 3 + 2];
      int hrb = SM_H + rowl * 64;
      int sw3 = (rowl & 3) << 4;
      #pragma unroll
      for (int u2 = 0; u2 < 4; ++u2) {
        float h0 = fmaxf(bb0r[u2*2]   + d0*wb0r[0][u2*2]   + d1*wb0r[1][u2*2]   + d2*wb0r[2][u2*2],   0.f);
        float h1 = fmaxf(bb0r[u2*2+1] + d0*wb0r[0][u2*2+1] + d1*wb0r[1][u2*2+1] + d2*wb0r[2][u2*2+1], 0.f);
        *(uint32_t*)(sm + hrb + ((q * 16 + u2 * 4) ^ sw3)) = pkbf(h0, h1);
      }
    }
    __syncthreads();

    // ---- P1: b1 MFMA (d_vec) + embedding gathers -> X i-part. wave wv owns rows 16wv..+16 ----
    {
      int hrow = 16 * wv + lr;
      v8s ah  = *(const v8s*)(sm + SM_H + hrow * 64 + ((lg * 16) ^ ((hrow & 3) << 4)));
      v8s wbl = *(const v8s*)(sm + SM_WB1T + lr * 64 + ((lg * 16) ^ ((lr & 3) << 4)));
      v8s wbh = *(const v8s*)(sm + SM_WB1T + (16 + lr) * 64 + ((lg * 16) ^ ((lr & 3) << 4)));
      float b0v = bb1l[lr], b1v = bb1l[16 + lr];
      v4f dv0 = {b0v, b0v, b0v, b0v};
      v4f dv1 = {b1v, b1v, b1v, b1v};
      dv0 = mfma16(ah, wbl, dv0);   // d_vec dims 0..15 (no relu)
      dv1 = mfma16(ah, wbh, dv1);   // d_vec dims 16..31
      #pragma unroll
      for (int j = 0; j < 4; ++j) {
        int mrow = 16 * wv + lg * 4 + j;
        int rr = r0 + mrow;
        int ic = cand[rr], ia = auth[rr], il = lang[rr];
        const int* tp = tags + rr * 5;
        int t0i = tp[0], t1i = tp[1], t2i = tp[2], t3i = tp[3], t4i = tp[4];
        float s0 = Ec[ic*32+lr] + Ea[ia*32+lr] + El[il*32+lr]
                 + (Et[t0i*32+lr]+Et[t1i*32+lr]+Et[t2i*32+lr]+Et[t3i*32+lr]+Et[t4i*32+lr]) * 0.2f
                 + dv0[j];
        int c1 = 16 + lr;
        float s1 = Ec[ic*32+c1] + Ea[ia*32+c1] + El[il*32+c1]
                 + (Et[t0i*32+c1]+Et[t1i*32+c1]+Et[t2i*32+c1]+Et[t3i*32+c1]+Et[t4i*32+c1]) * 0.2f
                 + dv1[j];
        *(uint32_t*)(sm + SM_X + mrow * 128 + ((64 + 4 * lr) ^ ((mrow & 7) << 4))) = pkbf(s0, s1);
      }
    }
    __syncthreads();

    // ---- t0 (64->256) + t1 (256->128) in two 128-col chunks; t1 accs persist in regs ----
    v4f acc2[2][4];
    #pragma unroll
    for (int p = 0; p < 2; ++p) {
      float bv = bt1l[wv * 32 + p * 16 + lr];
      #pragma unroll
      for (int m = 0; m < 4; ++m) acc2[p][m] = (v4f){bv, bv, bv, bv};
    }
    #pragma unroll
    for (int ch = 0; ch < 2; ++ch) {
      v4f a1[2][4];
      #pragma unroll
      for (int p = 0; p < 2; ++p) {
        float bv = bt0l[ch * 128 + wv * 32 + p * 16 + lr];
        #pragma unroll
        for (int m = 0; m < 4; ++m) a1[p][m] = (v4f){bv, bv, bv, bv};
      }
      #pragma unroll
      for (int ks = 0; ks < 2; ++ks) {
        v8s xa[4];
        #pragma unroll
        for (int m = 0; m < 4; ++m)
          xa[m] = *(const v8s*)(sm + SM_X + (m * 16 + lr) * 128 + ((ks * 64 + lg * 16) ^ ((lr & 7) << 4)));
        #pragma unroll
        for (int p = 0; p < 2; ++p) {
          int n = ch * 128 + wv * 32 + p * 16 + lr;
          v8s wb = *(const v8s*)(sm + SM_WT0T + n * 128 + ((ks * 64 + lg * 16) ^ ((n & 7) << 4)));
          #pragma unroll
          for (int m = 0; m < 4; ++m) a1[p][m] = mfma16(xa[m], wb, a1[p][m]);
        }
      }
      #pragma unroll
      for (int m = 0; m < 4; ++m) {
        #pragma unroll
        for (int j = 0; j < 4; ++j) {
          int row = m * 16 + lg * 4 + j;
          *(uint32_t*)(sm + SM_ACT1 + row * 256 + ((wv * 64 + 4 * lr) ^ ((row & 7) << 4)))
            = pkbf(fmaxf(a1[0][m][j], 0.f), fmaxf(a1[1][m][j], 0.f));
        }
      }
      __syncthreads();
      #pragma unroll
      for (int ks = 0; ks < 4; ++ks) {
        v8s aa[4];
        #pragma unroll
        for (int m = 0; m < 4; ++m)
          aa[m] = *(const v8s*)(sm + SM_ACT1 + (m * 16 + lr) * 256 + ((ks * 64 + lg * 16) ^ ((lr & 7) << 4)));
        #pragma unroll
        for (int p = 0; p < 2; ++p) {
          int n = wv * 32 + p * 16 + lr;
          v8s wb = *(const v8s*)(sm + SM_WT1T + n * 512 + ((ch * 256 + ks * 64 + lg * 16) ^ ((n & 7) << 4)));
          #pragma unroll
          for (int m = 0; m < 4; ++m) acc2[p][m] = mfma16(aa[m], wb, acc2[p][m]);
        }
      }
      __syncthreads();
    }
    // write act2 (relu, paired)
    #pragma unroll
    for (int m = 0; m < 4; ++m) {
      #pragma unroll
      for (int j = 0; j < 4; ++j) {
        int row = m * 16 + lg * 4 + j;
        *(uint32_t*)(sm + SM_ACT2 + row * 256 + ((wv * 64 + 4 * lr) ^ ((row & 7) << 4)))
          = pkbf(fmaxf(acc2[0][m][j], 0.f), fmaxf(acc2[1][m][j], 0.f));
      }
    }
    __syncthreads();

    // ---- t2 (128->64): wave wv owns cols 16wv..+16 ----
    {
      int n = wv * 16 + lr;
      float bv = bt2l[n];
      v4f a3[4];
      #pragma unroll
      for (int m = 0; m < 4; ++m) a3[m] = (v4f){bv, bv, bv, bv};
      #pragma unroll
      for (int ks = 0; ks < 4; ++ks) {
        v8s wb = *(const v8s*)(sm + SM_WT2T + n * 256 + ((ks * 64 + lg * 16) ^ ((n & 7) << 4)));
        #pragma unroll
        for (int m = 0; m < 4; ++m) {
          v8s aa = *(const v8s*)(sm + SM_ACT2 + (m * 16 + lr) * 256 + ((ks * 64 + lg * 16) ^ ((lr & 7) << 4)));
          a3[m] = mfma16(aa, wb, a3[m]);
        }
      }
      #pragma unroll
      for (int m = 0; m < 4; ++m) {
        #pragma unroll
        for (int j = 0; j < 4; ++j) {
          int row = m * 16 + lg * 4 + j;
          *(uint16_t*)(sm + SM_ACT3 + row * 128 + ((2 * n) ^ ((row & 7) << 4))) = bf16r(fmaxf(a3[m][j], 0.f));
        }
      }
    }
    __syncthreads();

    // ---- t3 (64->1): thread = (row rowl, k-slice q) ----
    {
      float acc = 0.f;
      int arb = SM_ACT3 + rowl * 128;
      int sw  = (rowl & 7) << 4;
      #pragma unroll
      for (int hf = 0; hf < 2; ++hf) {
        v8s av = *(const v8s*)(sm + arb + ((q * 32 + hf * 16) ^ sw));
        #pragma unroll
        for (int i = 0; i < 8; ++i) acc += bf2f(av[i]) * wt3r[hf * 8 + i];
      }
      acc += __shfl_xor(acc, 1);
      acc += __shfl_xor(acc, 2);
      if (q == 0) out[r0 + rowl] = acc + bt3v;
    }
  }
}

extern "C" void kernel_launch(void* const* d_in, const int* in_sizes, int n_in,
                              void* d_out, int out_size, void* d_ws, size_t ws_size,
                              hipStream_t stream) {
  const int*   hist  = (const int*)d_in[0];
  const int*   wish  = (const int*)d_in[1];
  const int*   cand  = (const int*)d_in[2];
  const int*   auth  = (const int*)d_in[3];
  const int*   lang  = (const int*)d_in[4];
  const int*   tags  = (const int*)d_in[5];
  const float* dense = (const float*)d_in[6];
  const float* Eh    = (const float*)d_in[7];
  const float* Ew    = (const float*)d_in[8];
  const float* Ec    = (const float*)d_in[9];
  const float* Ea    = (const float*)d_in[10];
  const float* El    = (const float*)d_in[11];
  const float* Et    = (const float*)d_in[12];
  const float* Wb0   = (const float*)d_in[13];
  const float* bb0   = (const float*)d_in[14];
  const float* Wb1   = (const float*)d_in[15];
  const float* bb1   = (const float*)d_in[16];
  const float* Wt0   = (const float*)d_in[17];
  const float* bt0   = (const float*)d_in[18];
  const float* Wt1   = (const float*)d_in[19];
  const float* bt1   = (const float*)d_in[20];
  const float* Wt2   = (const float*)d_in[21];
  const float* bt2   = (const float*)d_in[22];
  const float* Wt3   = (const float*)d_in[23];
  const float* bt3   = (const float*)d_in[24];
  float* uv  = (float*)d_ws;
  float* out = (float*)d_out;

  (void)hipFuncSetAttribute((const void*)k_fused,
                            hipFuncAttributeMaxDynamicSharedMemorySize, SM_BYTES);

  k_user<<<NB / 8, 256, 0, stream>>>(hist, wish, Eh, Ew, uv);
  k_fused<<<256, 256, SM_BYTES, stream>>>(cand, auth, lang, tags, dense,
      Ec, Ea, El, Et, Wb0, bb0, Wb1, bb1, Wt0, bt0, Wt1, bt1, Wt2, bt2, Wt3, bt3,
      uv, out, NROWS / 64 / 256);
}

// Round 2
// 361.497 us; speedup vs baseline: 1.0172x; 1.0172x over previous
//
#include <hip/hip_runtime.h>
#include <hip/hip_bf16.h>
#include <stdint.h>

#define NB 4096
#define NC 100
#define NROWS (NB*NC)        // 409600
#define NTILES (NROWS/64)    // 6400
#define GRID_F 1024
#define LH 200
#define LW 50

typedef short v8s __attribute__((ext_vector_type(8)));
typedef float v4f __attribute__((ext_vector_type(4)));

__device__ __forceinline__ v4f mfma16(v8s a, v8s b, v4f c) {
  return __builtin_amdgcn_mfma_f32_16x16x32_bf16(a, b, c, 0, 0, 0);
}

// packed f32x2 -> bf16x2 (lo = first arg), RNE
__device__ __forceinline__ uint32_t pkbf(float lo, float hi) {
  uint32_t r;
  asm("v_cvt_pk_bf16_f32 %0, %1, %2" : "=v"(r) : "v"(lo), "v"(hi));
  return r;
}

__device__ __forceinline__ uint16_t bf16r(float f) {
  uint32_t u = __builtin_bit_cast(uint32_t, f);
  u = (u + 0x7fffu + ((u >> 16) & 1u)) >> 16;
  return (uint16_t)u;
}

__device__ __forceinline__ float bf2f(short s) {
  return __builtin_bit_cast(float, (uint32_t)((uint16_t)s) << 16);
}

// ---------------- workspace layout ----------------
// [0, 512K)   : uv  (4096 x 32 f32)
// [512K, ...) : weight B-fragments, 114 frags x 1024B (frag = 64 lanes x 16B)
#define WS_FW 524288
#define FRAG_B1 0     // 2 frags
#define FRAG_T0 2     // 32 frags: g = wv*8 + ch*4 + ks*2 + p
#define FRAG_T1 34    // 64 frags: g = wv*16 + ch*8 + ks*2 + p
#define FRAG_T2 98    // 16 frags: g = wv*4 + ks
#define NFRAGS 114

// ---------------- kernel 0: build weight fragments ----------------
__global__ void k_prep(const float* __restrict__ Wb1, const float* __restrict__ Wt0,
                       const float* __restrict__ Wt1, const float* __restrict__ Wt2,
                       uint16_t* __restrict__ fb) {
  int f = blockIdx.x;          // fragment index
  int t = threadIdx.x;         // 256 threads, 2 elems each
  uint16_t res[2];
  #pragma unroll
  for (int e2 = 0; e2 < 2; ++e2) {
    int e = t * 2 + e2;        // 0..511
    int l = e >> 3, i = e & 7;
    int lr = l & 15, lg = l >> 4;
    float v;
    if (f < FRAG_T0) {                       // Wb1: h = f
      v = Wb1[(lg * 8 + i) * 32 + f * 16 + lr];
    } else if (f < FRAG_T1) {                // Wt0
      int g = f - FRAG_T0;
      int wv = g >> 3, ch = (g >> 2) & 1, ks = (g >> 1) & 1, p = g & 1;
      int n = ch * 128 + wv * 32 + p * 16 + lr;
      int kl = ks * 32 + lg * 8 + i;         // 0..63 (X storage order)
      int ok = (kl < 32) ? kl : 32 + (((kl & 31) >> 1) + ((kl & 1) << 4));
      v = Wt0[ok * 256 + n];
    } else if (f < FRAG_T2) {                // Wt1
      int g = f - FRAG_T1;
      int wv = g >> 4, ch = (g >> 3) & 1, ks = (g >> 1) & 3, p = g & 1;
      int n = wv * 32 + p * 16 + lr;
      int kl = ks * 32 + lg * 8 + i;         // 0..127 (act1 storage order)
      int ok = ch * 128 + (kl & ~31) + ((kl & 31) >> 1) + ((kl & 1) << 4);
      v = Wt1[ok * 128 + n];
    } else {                                 // Wt2
      int g = f - FRAG_T2;
      int wv = g >> 2, ks = g & 3;
      int n = wv * 16 + lr;
      int kl = ks * 32 + lg * 8 + i;         // 0..127 (act2 storage order)
      int ok = (kl & ~31) + ((kl & 31) >> 1) + ((kl & 1) << 4);
      v = Wt2[ok * 64 + n];
    }
    res[e2] = bf16r(v);
  }
  *(uint32_t*)(fb + (size_t)f * 512 + t * 2) = (uint32_t)res[0] | ((uint32_t)res[1] << 16);
}

// ---------------- kernel 1: user vector (hist/wish mean pool) ----------------
__global__ void k_user(const int* __restrict__ hist, const int* __restrict__ wish,
                       const float* __restrict__ Eh, const float* __restrict__ Ew,
                       float* __restrict__ uv) {
  int t = threadIdx.x;
  int d = t & 31;
  int r = (blockIdx.x << 3) + (t >> 5);
  const int* hr = hist + r * LH;
  float s = 0.f;
  #pragma unroll 8
  for (int j = 0; j < LH; ++j) s += Eh[hr[j] * 32 + d];
  float su = s * (1.0f / LH);
  const int* wr = wish + r * LW;
  s = 0.f;
  #pragma unroll 5
  for (int j = 0; j < LW; ++j) s += Ew[wr[j] * 32 + d];
  uv[r * 32 + d] = su + s * (1.0f / LW);
}

// ---------------- kernel 2: fused item pipeline ----------------
// LDS: activations only. Rows >=128B: swz byte^=((row&7)<<4); 64B rows: (row&3)<<4.
#define SM_BIAS 0        // bb1[32] bt0[256] bt1[128] bt2[64] f32 = 1920
#define SM_X    1920     // [64][128B] = 8192 (cols 0..31 u natural, 32..63 paired)
#define SM_ACT3 10112    // [64][128B] = 8192 (H aliased below)
#define SM_H    10112    // [64][64B]  = 4096
#define SM_ACT  18304    // [64][256B] = 16384 (act1 chunk, then act2)
#define SM_BYTES 34688

__global__ __launch_bounds__(256, 4)
void k_fused(const int* __restrict__ cand, const int* __restrict__ auth,
             const int* __restrict__ lang, const int* __restrict__ tags,
             const float* __restrict__ dense,
             const float* __restrict__ Ec, const float* __restrict__ Ea,
             const float* __restrict__ El, const float* __restrict__ Et,
             const float* __restrict__ Wb0, const float* __restrict__ bb0,
             const float* __restrict__ bb1, const float* __restrict__ bt0,
             const float* __restrict__ bt1, const float* __restrict__ bt2,
             const float* __restrict__ Wt3, const float* __restrict__ bt3,
             const float* __restrict__ uvec, const uint16_t* __restrict__ fw,
             float* __restrict__ out) {
  extern __shared__ char sm[];
  const char* fwp = (const char*)fw;
  const int t = threadIdx.x;
  const int l = t & 63, wv = t >> 6;
  const int lr = l & 15, lg = l >> 4;
  const int q = t & 3, rowl = t >> 2;

  // ---- stage biases ----
  float* bb1l = (float*)(sm + SM_BIAS);
  float* bt0l = bb1l + 32;
  float* bt1l = bt0l + 256;
  float* bt2l = bt1l + 128;
  if (t < 32)  bb1l[t] = bb1[t];
  bt0l[t] = bt0[t];
  if (t < 128) bt1l[t] = bt1[t];
  if (t < 64)  bt2l[t] = bt2[t];

  // hoisted per-thread constants
  float wb0r[3][8], bb0r[8], wt3r[16];
  #pragma unroll
  for (int j = 0; j < 8; ++j) {
    bb0r[j] = bb0[q * 8 + j];
    #pragma unroll
    for (int f = 0; f < 3; ++f) wb0r[f][j] = Wb0[f * 32 + q * 8 + j];
  }
  #pragma unroll
  for (int j = 0; j < 16; ++j) wt3r[j] = Wt3[q * 16 + j];
  const float bt3v = bt3[0];

  for (int tile = blockIdx.x; tile < NTILES; tile += GRID_F) {
    const int r0 = tile << 6;
    __syncthreads();   // staging (tile 0); ACT3/H + X reuse across tiles

    // ---- P0: X u-part + bottom-MLP layer0 (h) ----
    {
      int r = r0 + rowl;
      int b = r / 100;
      const float* up = uvec + b * 32 + q * 8;
      int xrb = SM_X + rowl * 128;
      int sw  = (rowl & 7) << 4;
      #pragma unroll
      for (int u2 = 0; u2 < 4; ++u2)
        *(uint32_t*)(sm + xrb + ((q * 16 + u2 * 4) ^ sw)) = pkbf(up[u2 * 2], up[u2 * 2 + 1]);
      float d0 = dense[r * 3 + 0], d1 = dense[r * 3 + 1], d2 = dense[r * 3 + 2];
      int hrb = SM_H + rowl * 64;
      int sw3 = (rowl & 3) << 4;
      #pragma unroll
      for (int u2 = 0; u2 < 4; ++u2) {
        float h0 = fmaxf(bb0r[u2*2]   + d0*wb0r[0][u2*2]   + d1*wb0r[1][u2*2]   + d2*wb0r[2][u2*2],   0.f);
        float h1 = fmaxf(bb0r[u2*2+1] + d0*wb0r[0][u2*2+1] + d1*wb0r[1][u2*2+1] + d2*wb0r[2][u2*2+1], 0.f);
        *(uint32_t*)(sm + hrb + ((q * 16 + u2 * 4) ^ sw3)) = pkbf(h0, h1);
      }
    }
    __syncthreads();

    // ---- P1: b1 MFMA (d_vec) + embedding gathers -> X i-part ----
    {
      int hrow = 16 * wv + lr;
      v8s ah  = *(const v8s*)(sm + SM_H + hrow * 64 + ((lg * 16) ^ ((hrow & 3) << 4)));
      v8s wbl = *(const v8s*)(fwp + (size_t)(FRAG_B1 + 0) * 1024 + l * 16);
      v8s wbh = *(const v8s*)(fwp + (size_t)(FRAG_B1 + 1) * 1024 + l * 16);
      float b0v = bb1l[lr], b1v = bb1l[16 + lr];
      v4f dv0 = {b0v, b0v, b0v, b0v};
      v4f dv1 = {b1v, b1v, b1v, b1v};
      dv0 = mfma16(ah, wbl, dv0);
      dv1 = mfma16(ah, wbh, dv1);
      #pragma unroll
      for (int j = 0; j < 4; ++j) {
        int mrow = 16 * wv + lg * 4 + j;
        int rr = r0 + mrow;
        int ic = cand[rr], ia = auth[rr], il = lang[rr];
        const int* tp = tags + rr * 5;
        int t0i = tp[0], t1i = tp[1], t2i = tp[2], t3i = tp[3], t4i = tp[4];
        float s0 = Ec[ic*32+lr] + Ea[ia*32+lr] + El[il*32+lr]
                 + (Et[t0i*32+lr]+Et[t1i*32+lr]+Et[t2i*32+lr]+Et[t3i*32+lr]+Et[t4i*32+lr]) * 0.2f
                 + dv0[j];
        int c1 = 16 + lr;
        float s1 = Ec[ic*32+c1] + Ea[ia*32+c1] + El[il*32+c1]
                 + (Et[t0i*32+c1]+Et[t1i*32+c1]+Et[t2i*32+c1]+Et[t3i*32+c1]+Et[t4i*32+c1]) * 0.2f
                 + dv1[j];
        *(uint32_t*)(sm + SM_X + mrow * 128 + ((64 + 4 * lr) ^ ((mrow & 7) << 4))) = pkbf(s0, s1);
      }
    }
    __syncthreads();

    // ---- t0 (64->256) + t1 (256->128) in two 128-col chunks ----
    v4f acc2[2][4];
    #pragma unroll
    for (int p = 0; p < 2; ++p) {
      float bv = bt1l[wv * 32 + p * 16 + lr];
      #pragma unroll
      for (int m = 0; m < 4; ++m) acc2[p][m] = (v4f){bv, bv, bv, bv};
    }
    #pragma unroll
    for (int ch = 0; ch < 2; ++ch) {
      v4f a1[2][4];
      #pragma unroll
      for (int p = 0; p < 2; ++p) {
        float bv = bt0l[ch * 128 + wv * 32 + p * 16 + lr];
        #pragma unroll
        for (int m = 0; m < 4; ++m) a1[p][m] = (v4f){bv, bv, bv, bv};
      }
      #pragma unroll
      for (int ks = 0; ks < 2; ++ks) {
        v8s xa[4];
        #pragma unroll
        for (int m = 0; m < 4; ++m)
          xa[m] = *(const v8s*)(sm + SM_X + (m * 16 + lr) * 128 + ((ks * 64 + lg * 16) ^ ((lr & 7) << 4)));
        #pragma unroll
        for (int p = 0; p < 2; ++p) {
          v8s wb = *(const v8s*)(fwp + (size_t)(FRAG_T0 + wv * 8 + ch * 4 + ks * 2 + p) * 1024 + l * 16);
          #pragma unroll
          for (int m = 0; m < 4; ++m) a1[p][m] = mfma16(xa[m], wb, a1[p][m]);
        }
      }
      #pragma unroll
      for (int m = 0; m < 4; ++m) {
        #pragma unroll
        for (int j = 0; j < 4; ++j) {
          int row = m * 16 + lg * 4 + j;
          *(uint32_t*)(sm + SM_ACT + row * 256 + ((wv * 64 + 4 * lr) ^ ((row & 7) << 4)))
            = pkbf(fmaxf(a1[0][m][j], 0.f), fmaxf(a1[1][m][j], 0.f));
        }
      }
      __syncthreads();
      #pragma unroll
      for (int ks = 0; ks < 4; ++ks) {
        v8s aa[4];
        #pragma unroll
        for (int m = 0; m < 4; ++m)
          aa[m] = *(const v8s*)(sm + SM_ACT + (m * 16 + lr) * 256 + ((ks * 64 + lg * 16) ^ ((lr & 7) << 4)));
        #pragma unroll
        for (int p = 0; p < 2; ++p) {
          v8s wb = *(const v8s*)(fwp + (size_t)(FRAG_T1 + wv * 16 + ch * 8 + ks * 2 + p) * 1024 + l * 16);
          #pragma unroll
          for (int m = 0; m < 4; ++m) acc2[p][m] = mfma16(aa[m], wb, acc2[p][m]);
        }
      }
      __syncthreads();
    }
    // act2 (relu, paired) into the same ACT buffer
    #pragma unroll
    for (int m = 0; m < 4; ++m) {
      #pragma unroll
      for (int j = 0; j < 4; ++j) {
        int row = m * 16 + lg * 4 + j;
        *(uint32_t*)(sm + SM_ACT + row * 256 + ((wv * 64 + 4 * lr) ^ ((row & 7) << 4)))
          = pkbf(fmaxf(acc2[0][m][j], 0.f), fmaxf(acc2[1][m][j], 0.f));
      }
    }
    __syncthreads();

    // ---- t2 (128->64) ----
    {
      int n2 = wv * 16 + lr;
      float bv = bt2l[n2];
      v4f a3[4];
      #pragma unroll
      for (int m = 0; m < 4; ++m) a3[m] = (v4f){bv, bv, bv, bv};
      #pragma unroll
      for (int ks = 0; ks < 4; ++ks) {
        v8s wb = *(const v8s*)(fwp + (size_t)(FRAG_T2 + wv * 4 + ks) * 1024 + l * 16);
        #pragma unroll
        for (int m = 0; m < 4; ++m) {
          v8s aa = *(const v8s*)(sm + SM_ACT + (m * 16 + lr) * 256 + ((ks * 64 + lg * 16) ^ ((lr & 7) << 4)));
          a3[m] = mfma16(aa, wb, a3[m]);
        }
      }
      #pragma unroll
      for (int m = 0; m < 4; ++m) {
        #pragma unroll
        for (int j = 0; j < 4; ++j) {
          int row = m * 16 + lg * 4 + j;
          *(uint16_t*)(sm + SM_ACT3 + row * 128 + ((2 * n2) ^ ((row & 7) << 4))) = bf16r(fmaxf(a3[m][j], 0.f));
        }
      }
    }
    __syncthreads();

    // ---- t3 (64->1) ----
    {
      float acc = 0.f;
      int arb = SM_ACT3 + rowl * 128;
      int sw  = (rowl & 7) << 4;
      #pragma unroll
      for (int hf = 0; hf < 2; ++hf) {
        v8s av = *(const v8s*)(sm + arb + ((q * 32 + hf * 16) ^ sw));
        #pragma unroll
        for (int i = 0; i < 8; ++i) acc += bf2f(av[i]) * wt3r[hf * 8 + i];
      }
      acc += __shfl_xor(acc, 1);
      acc += __shfl_xor(acc, 2);
      if (q == 0) out[r0 + rowl] = acc + bt3v;
    }
  }
}

extern "C" void kernel_launch(void* const* d_in, const int* in_sizes, int n_in,
                              void* d_out, int out_size, void* d_ws, size_t ws_size,
                              hipStream_t stream) {
  const int*   hist  = (const int*)d_in[0];
  const int*   wish  = (const int*)d_in[1];
  const int*   cand  = (const int*)d_in[2];
  const int*   auth  = (const int*)d_in[3];
  const int*   lang  = (const int*)d_in[4];
  const int*   tags  = (const int*)d_in[5];
  const float* dense = (const float*)d_in[6];
  const float* Eh    = (const float*)d_in[7];
  const float* Ew    = (const float*)d_in[8];
  const float* Ec    = (const float*)d_in[9];
  const float* Ea    = (const float*)d_in[10];
  const float* El    = (const float*)d_in[11];
  const float* Et    = (const float*)d_in[12];
  const float* Wb0   = (const float*)d_in[13];
  const float* bb0   = (const float*)d_in[14];
  const float* Wb1   = (const float*)d_in[15];
  const float* bb1   = (const float*)d_in[16];
  const float* Wt0   = (const float*)d_in[17];
  const float* bt0   = (const float*)d_in[18];
  const float* Wt1   = (const float*)d_in[19];
  const float* bt1   = (const float*)d_in[20];
  const float* Wt2   = (const float*)d_in[21];
  const float* bt2   = (const float*)d_in[22];
  const float* Wt3   = (const float*)d_in[23];
  const float* bt3   = (const float*)d_in[24];
  char* wsb = (char*)d_ws;
  float* uv = (float*)wsb;
  uint16_t* fw = (uint16_t*)(wsb + WS_FW);
  float* out = (float*)d_out;

  (void)hipFuncSetAttribute((const void*)k_fused,
                            hipFuncAttributeMaxDynamicSharedMemorySize, SM_BYTES);

  k_prep<<<NFRAGS, 256, 0, stream>>>(Wb1, Wt0, Wt1, Wt2, fw);
  k_user<<<NB / 8, 256, 0, stream>>>(hist, wish, Eh, Ew, uv);
  k_fused<<<GRID_F, 256, SM_BYTES, stream>>>(cand, auth, lang, tags, dense,
      Ec, Ea, El, Et, Wb0, bb0, bb1, bt0, bt1, bt2, Wt3, bt3, uv, fw, out);
}

// Round 3
// 299.648 us; speedup vs baseline: 1.2272x; 1.2064x over previous
//
#include <hip/hip_runtime.h>
#include <hip/hip_bf16.h>
#include <stdint.h>

#define NB 4096
#define NC 100
#define NROWS (NB*NC)        // 409600
#define NTILES (NROWS/64)    // 6400
#define GRID_F 768
#define LH 200
#define LW 50

typedef short v8s __attribute__((ext_vector_type(8)));
typedef float v4f __attribute__((ext_vector_type(4)));
typedef float v2f __attribute__((ext_vector_type(2)));

__device__ __forceinline__ v4f mfma16(v8s a, v8s b, v4f c) {
  return __builtin_amdgcn_mfma_f32_16x16x32_bf16(a, b, c, 0, 0, 0);
}

// packed f32x2 -> bf16x2 (lo = first arg), RNE
__device__ __forceinline__ uint32_t pkbf(float lo, float hi) {
  uint32_t r;
  asm("v_cvt_pk_bf16_f32 %0, %1, %2" : "=v"(r) : "v"(lo), "v"(hi));
  return r;
}

__device__ __forceinline__ uint16_t bf16r(float f) {
  uint32_t u = __builtin_bit_cast(uint32_t, f);
  u = (u + 0x7fffu + ((u >> 16) & 1u)) >> 16;
  return (uint16_t)u;
}

__device__ __forceinline__ float bf2f(short s) {
  return __builtin_bit_cast(float, (uint32_t)((uint16_t)s) << 16);
}

__device__ __forceinline__ int ntli(const int* p) { return __builtin_nontemporal_load(p); }
__device__ __forceinline__ float ntlf(const float* p) { return __builtin_nontemporal_load(p); }

// ---------------- workspace layout ----------------
// [0, 512K)   : uv  (4096 x 32 f32)
// [512K, ...) : weight B-fragments, 114 frags x 1024B (frag = 64 lanes x 16B)
#define WS_FW 524288
#define FRAG_B1 0     // 2 frags (even/odd output cols)
#define FRAG_T0 2     // 32 frags: g = wv*8 + ch*4 + ks*2 + p   (k identity)
#define FRAG_T1 34    // 64 frags: g = wv*16 + ch*8 + ks*2 + p  (k PERM32-paired)
#define FRAG_T2 98    // 16 frags: g = wv*4 + ks                (k PERM32-paired)
#define NFRAGS 114

// ---------------- kernel 0: build weight fragments ----------------
__global__ void k_prep(const float* __restrict__ Wb1, const float* __restrict__ Wt0,
                       const float* __restrict__ Wt1, const float* __restrict__ Wt2,
                       uint16_t* __restrict__ fb) {
  int f = blockIdx.x;
  int t = threadIdx.x;
  uint16_t res[2];
  #pragma unroll
  for (int e2 = 0; e2 < 2; ++e2) {
    int e = t * 2 + e2;        // 0..511
    int l = e >> 3, i = e & 7;
    int lr = l & 15, lg = l >> 4;
    float v;
    if (f < FRAG_T0) {                       // Wb1: frag f holds output cols 2*lr+f
      v = Wb1[(lg * 8 + i) * 32 + 2 * lr + f];
    } else if (f < FRAG_T1) {                // Wt0 (k identity: X cols natural)
      int g = f - FRAG_T0;
      int wv = g >> 3, ch = (g >> 2) & 1, ks = (g >> 1) & 1, p = g & 1;
      int n = ch * 128 + wv * 32 + p * 16 + lr;
      int kl = ks * 32 + lg * 8 + i;         // 0..63
      v = Wt0[kl * 256 + n];
    } else if (f < FRAG_T2) {                // Wt1 (act1 pkbf-paired order)
      int g = f - FRAG_T1;
      int wv = g >> 4, ch = (g >> 3) & 1, ks = (g >> 1) & 3, p = g & 1;
      int n = wv * 32 + p * 16 + lr;
      int kl = ks * 32 + lg * 8 + i;         // 0..127
      int ok = ch * 128 + (kl & ~31) + ((kl & 31) >> 1) + ((kl & 1) << 4);
      v = Wt1[ok * 128 + n];
    } else {                                 // Wt2 (act2 pkbf-paired order)
      int g = f - FRAG_T2;
      int wv = g >> 2, ks = g & 3;
      int n = wv * 16 + lr;
      int kl = ks * 32 + lg * 8 + i;
      int ok = (kl & ~31) + ((kl & 31) >> 1) + ((kl & 1) << 4);
      v = Wt2[ok * 64 + n];
    }
    res[e2] = bf16r(v);
  }
  *(uint32_t*)(fb + (size_t)f * 512 + t * 2) = (uint32_t)res[0] | ((uint32_t)res[1] << 16);
}

// ---------------- kernel 1: user vector ----------------
__global__ void k_user(const int* __restrict__ hist, const int* __restrict__ wish,
                       const float* __restrict__ Eh, const float* __restrict__ Ew,
                       float* __restrict__ uv) {
  int t = threadIdx.x;
  int d = t & 31;
  int r = (blockIdx.x << 3) + (t >> 5);
  const int* hr = hist + r * LH;
  float s = 0.f;
  #pragma unroll 8
  for (int j = 0; j < LH; ++j) s += Eh[ntli(hr + j) * 32 + d];
  float su = s * (1.0f / LH);
  const int* wr = wish + r * LW;
  s = 0.f;
  #pragma unroll 5
  for (int j = 0; j < LW; ++j) s += Ew[ntli(wr + j) * 32 + d];
  uv[r * 32 + d] = su + s * (1.0f / LW);
}

// ---------------- kernel 2: fused item pipeline ----------------
// LDS: activations + small constants. Rows >=128B: swz byte^=((row&7)<<4); 64B rows: (row&3)<<4.
#define SM_CONST 0       // 672 f32 = 2688 B (see cf offsets below)
#define SM_X     2688    // [64][128B] = 8192 (cols 0..31 u natural, 32..63 i natural-paired)
#define SM_ACT3  10880   // [64][128B] = 8192 (H aliased below)
#define SM_H     10880   // [64][64B]  = 4096
#define SM_ACT   19072   // [64][256B] = 16384 (act1 chunk, then act2)
#define SM_BYTES 35456
// cf (f32 idx): 0 bb1[32] | 32 bt0[256] | 288 bt1[128] | 416 bt2[64] | 480 bb0[32] | 512 Wb0[96] | 608 Wt3[64]

__global__ __launch_bounds__(256, 3)
void k_fused(const int* __restrict__ cand, const int* __restrict__ auth,
             const int* __restrict__ lang, const int* __restrict__ tags,
             const float* __restrict__ dense,
             const float* __restrict__ Ec, const float* __restrict__ Ea,
             const float* __restrict__ El, const float* __restrict__ Et,
             const float* __restrict__ Wb0, const float* __restrict__ bb0,
             const float* __restrict__ bb1, const float* __restrict__ bt0,
             const float* __restrict__ bt1, const float* __restrict__ bt2,
             const float* __restrict__ Wt3, const float* __restrict__ bt3,
             const float* __restrict__ uvec, const uint16_t* __restrict__ fw,
             float* __restrict__ out) {
  extern __shared__ char sm[];
  const char* fwp = (const char*)fw;
  float* cf = (float*)(sm + SM_CONST);
  const int t = threadIdx.x;
  const int l = t & 63, wv = t >> 6;
  const int lr = l & 15, lg = l >> 4;
  const int q = t & 3, rowl = t >> 2;

  // ---- stage constants ----
  cf[32 + t] = bt0[t];
  if (t < 128) cf[288 + t] = bt1[t];
  if (t < 64)  { cf[416 + t] = bt2[t]; cf[608 + t] = Wt3[t]; }
  if (t < 32)  { cf[t] = bb1[t]; cf[480 + t] = bb0[t]; }
  if (t < 96)  cf[512 + t] = Wb0[t];
  const float bt3v = bt3[0];

  for (int tile = blockIdx.x; tile < NTILES; tile += GRID_F) {
    const int r0 = tile << 6;
    __syncthreads();   // staging (tile 0); ACT3/H + X reuse across tiles

    // ---- P0: X u-part + bottom-MLP layer0 (h) ----
    {
      int r = r0 + rowl;
      int b = r / 100;
      const float* up = uvec + b * 32 + q * 8;
      int xrb = SM_X + rowl * 128;
      int sw  = (rowl & 7) << 4;
      #pragma unroll
      for (int u2 = 0; u2 < 4; ++u2)
        *(uint32_t*)(sm + xrb + ((q * 16 + u2 * 4) ^ sw)) = pkbf(up[u2 * 2], up[u2 * 2 + 1]);
      float d0 = ntlf(dense + r * 3 + 0), d1 = ntlf(dense + r * 3 + 1), d2 = ntlf(dense + r * 3 + 2);
      const float* bb0l = cf + 480;
      const float* w0a = cf + 512, *w0b = cf + 544, *w0c = cf + 576;
      int hrb = SM_H + rowl * 64;
      int sw3 = (rowl & 3) << 4;
      #pragma unroll
      for (int u2 = 0; u2 < 4; ++u2) {
        int e0 = q * 8 + u2 * 2, e1 = e0 + 1;
        float h0 = fmaxf(bb0l[e0] + d0 * w0a[e0] + d1 * w0b[e0] + d2 * w0c[e0], 0.f);
        float h1 = fmaxf(bb0l[e1] + d0 * w0a[e1] + d1 * w0b[e1] + d2 * w0c[e1], 0.f);
        *(uint32_t*)(sm + hrb + ((q * 16 + u2 * 4) ^ sw3)) = pkbf(h0, h1);
      }
    }
    __syncthreads();

    // ---- P1: b1 MFMA (d_vec, even/odd cols) + paired embedding gathers -> X i-part ----
    {
      int hrow = 16 * wv + lr;
      v8s ah  = *(const v8s*)(sm + SM_H + hrow * 64 + ((lg * 16) ^ ((hrow & 3) << 4)));
      v8s wbl = *(const v8s*)(fwp + (size_t)(FRAG_B1 + 0) * 1024 + l * 16);
      v8s wbh = *(const v8s*)(fwp + (size_t)(FRAG_B1 + 1) * 1024 + l * 16);
      float b0v = cf[2 * lr], b1v = cf[2 * lr + 1];
      v4f dv0 = {b0v, b0v, b0v, b0v};
      v4f dv1 = {b1v, b1v, b1v, b1v};
      dv0 = mfma16(ah, wbl, dv0);   // i dims 2*lr
      dv1 = mfma16(ah, wbh, dv1);   // i dims 2*lr+1
      #pragma unroll
      for (int j = 0; j < 4; ++j) {
        int mrow = 16 * wv + lg * 4 + j;
        int rr = r0 + mrow;
        int ic = ntli(cand + rr), ia = ntli(auth + rr), il = ntli(lang + rr);
        const int* tp = tags + rr * 5;
        int t0i = ntli(tp), t1i = ntli(tp + 1), t2i = ntli(tp + 2), t3i = ntli(tp + 3), t4i = ntli(tp + 4);
        int co = 2 * lr;
        v2f ec = *(const v2f*)(Ec + ic * 32 + co);
        v2f ea = *(const v2f*)(Ea + ia * 32 + co);
        v2f el = *(const v2f*)(El + il * 32 + co);
        v2f e0 = *(const v2f*)(Et + t0i * 32 + co);
        v2f e1 = *(const v2f*)(Et + t1i * 32 + co);
        v2f e2 = *(const v2f*)(Et + t2i * 32 + co);
        v2f e3 = *(const v2f*)(Et + t3i * 32 + co);
        v2f e4 = *(const v2f*)(Et + t4i * 32 + co);
        float s0 = ec[0] + ea[0] + el[0] + (e0[0] + e1[0] + e2[0] + e3[0] + e4[0]) * 0.2f + dv0[j];
        float s1 = ec[1] + ea[1] + el[1] + (e0[1] + e1[1] + e2[1] + e3[1] + e4[1]) * 0.2f + dv1[j];
        *(uint32_t*)(sm + SM_X + mrow * 128 + ((64 + 4 * lr) ^ ((mrow & 7) << 4))) = pkbf(s0, s1);
      }
    }
    __syncthreads();

    // ---- t0 (64->256) + t1 (256->128) in two 128-col chunks; t1 accs persist ----
    v4f acc2[2][4];
    #pragma unroll
    for (int ch = 0; ch < 2; ++ch) {
      v4f a1[2][4];
      #pragma unroll
      for (int p = 0; p < 2; ++p) {
        float bv = cf[32 + ch * 128 + wv * 32 + p * 16 + lr];
        #pragma unroll
        for (int m = 0; m < 4; ++m) a1[p][m] = (v4f){bv, bv, bv, bv};
      }
      #pragma unroll
      for (int ks = 0; ks < 2; ++ks) {
        v8s xa[4];
        #pragma unroll
        for (int m = 0; m < 4; ++m)
          xa[m] = *(const v8s*)(sm + SM_X + (m * 16 + lr) * 128 + ((ks * 64 + lg * 16) ^ ((lr & 7) << 4)));
        #pragma unroll
        for (int p = 0; p < 2; ++p) {
          v8s wb = *(const v8s*)(fwp + (size_t)(FRAG_T0 + wv * 8 + ch * 4 + ks * 2 + p) * 1024 + l * 16);
          #pragma unroll
          for (int m = 0; m < 4; ++m) a1[p][m] = mfma16(xa[m], wb, a1[p][m]);
        }
      }
      #pragma unroll
      for (int m = 0; m < 4; ++m) {
        #pragma unroll
        for (int j = 0; j < 4; ++j) {
          int row = m * 16 + lg * 4 + j;
          *(uint32_t*)(sm + SM_ACT + row * 256 + ((wv * 64 + 4 * lr) ^ ((row & 7) << 4)))
            = pkbf(fmaxf(a1[0][m][j], 0.f), fmaxf(a1[1][m][j], 0.f));
        }
      }
      __syncthreads();
      if (ch == 0) {   // delayed init: don't keep acc2 live through t0
        #pragma unroll
        for (int p = 0; p < 2; ++p) {
          float bv = cf[288 + wv * 32 + p * 16 + lr];
          #pragma unroll
          for (int m = 0; m < 4; ++m) acc2[p][m] = (v4f){bv, bv, bv, bv};
        }
      }
      #pragma unroll
      for (int ks = 0; ks < 4; ++ks) {
        v8s aa[4];
        #pragma unroll
        for (int m = 0; m < 4; ++m)
          aa[m] = *(const v8s*)(sm + SM_ACT + (m * 16 + lr) * 256 + ((ks * 64 + lg * 16) ^ ((lr & 7) << 4)));
        #pragma unroll
        for (int p = 0; p < 2; ++p) {
          v8s wb = *(const v8s*)(fwp + (size_t)(FRAG_T1 + wv * 16 + ch * 8 + ks * 2 + p) * 1024 + l * 16);
          #pragma unroll
          for (int m = 0; m < 4; ++m) acc2[p][m] = mfma16(aa[m], wb, acc2[p][m]);
        }
      }
      __syncthreads();
    }
    // act2 (relu, paired) into the same ACT buffer
    #pragma unroll
    for (int m = 0; m < 4; ++m) {
      #pragma unroll
      for (int j = 0; j < 4; ++j) {
        int row = m * 16 + lg * 4 + j;
        *(uint32_t*)(sm + SM_ACT + row * 256 + ((wv * 64 + 4 * lr) ^ ((row & 7) << 4)))
          = pkbf(fmaxf(acc2[0][m][j], 0.f), fmaxf(acc2[1][m][j], 0.f));
      }
    }
    __syncthreads();

    // ---- t2 (128->64) ----
    {
      int n2 = wv * 16 + lr;
      float bv = cf[416 + n2];
      v4f a3[4];
      #pragma unroll
      for (int m = 0; m < 4; ++m) a3[m] = (v4f){bv, bv, bv, bv};
      #pragma unroll
      for (int ks = 0; ks < 4; ++ks) {
        v8s wb = *(const v8s*)(fwp + (size_t)(FRAG_T2 + wv * 4 + ks) * 1024 + l * 16);
        #pragma unroll
        for (int m = 0; m < 4; ++m) {
          v8s aa = *(const v8s*)(sm + SM_ACT + (m * 16 + lr) * 256 + ((ks * 64 + lg * 16) ^ ((lr & 7) << 4)));
          a3[m] = mfma16(aa, wb, a3[m]);
        }
      }
      #pragma unroll
      for (int m = 0; m < 4; ++m) {
        #pragma unroll
        for (int j = 0; j < 4; ++j) {
          int row = m * 16 + lg * 4 + j;
          *(uint16_t*)(sm + SM_ACT3 + row * 128 + ((2 * n2) ^ ((row & 7) << 4))) = bf16r(fmaxf(a3[m][j], 0.f));
        }
      }
    }
    __syncthreads();

    // ---- t3 (64->1) ----
    {
      float acc = 0.f;
      int arb = SM_ACT3 + rowl * 128;
      int sw  = (rowl & 7) << 4;
      const float* wt3l = cf + 608;
      #pragma unroll
      for (int hf = 0; hf < 2; ++hf) {
        v8s av = *(const v8s*)(sm + arb + ((q * 32 + hf * 16) ^ sw));
        #pragma unroll
        for (int i = 0; i < 8; ++i) acc += bf2f(av[i]) * wt3l[q * 16 + hf * 8 + i];
      }
      acc += __shfl_xor(acc, 1);
      acc += __shfl_xor(acc, 2);
      if (q == 0) __builtin_nontemporal_store(acc + bt3v, out + r0 + rowl);
    }
  }
}

extern "C" void kernel_launch(void* const* d_in, const int* in_sizes, int n_in,
                              void* d_out, int out_size, void* d_ws, size_t ws_size,
                              hipStream_t stream) {
  const int*   hist  = (const int*)d_in[0];
  const int*   wish  = (const int*)d_in[1];
  const int*   cand  = (const int*)d_in[2];
  const int*   auth  = (const int*)d_in[3];
  const int*   lang  = (const int*)d_in[4];
  const int*   tags  = (const int*)d_in[5];
  const float* dense = (const float*)d_in[6];
  const float* Eh    = (const float*)d_in[7];
  const float* Ew    = (const float*)d_in[8];
  const float* Ec    = (const float*)d_in[9];
  const float* Ea    = (const float*)d_in[10];
  const float* El    = (const float*)d_in[11];
  const float* Et    = (const float*)d_in[12];
  const float* Wb0   = (const float*)d_in[13];
  const float* bb0   = (const float*)d_in[14];
  const float* Wb1   = (const float*)d_in[15];
  const float* bb1   = (const float*)d_in[16];
  const float* Wt0   = (const float*)d_in[17];
  const float* bt0   = (const float*)d_in[18];
  const float* Wt1   = (const float*)d_in[19];
  const float* bt1   = (const float*)d_in[20];
  const float* Wt2   = (const float*)d_in[21];
  const float* bt2   = (const float*)d_in[22];
  const float* Wt3   = (const float*)d_in[23];
  const float* bt3   = (const float*)d_in[24];
  char* wsb = (char*)d_ws;
  float* uv = (float*)wsb;
  uint16_t* fw = (uint16_t*)(wsb + WS_FW);
  float* out = (float*)d_out;

  (void)hipFuncSetAttribute((const void*)k_fused,
                            hipFuncAttributeMaxDynamicSharedMemorySize, SM_BYTES);

  k_prep<<<NFRAGS, 256, 0, stream>>>(Wb1, Wt0, Wt1, Wt2, fw);
  k_user<<<NB / 8, 256, 0, stream>>>(hist, wish, Eh, Ew, uv);
  k_fused<<<GRID_F, 256, SM_BYTES, stream>>>(cand, auth, lang, tags, dense,
      Ec, Ea, El, Et, Wb0, bb0, bb1, bt0, bt1, bt2, Wt3, bt3, uv, fw, out);
}

// Round 4
// 290.174 us; speedup vs baseline: 1.2672x; 1.0327x over previous
//
#include <hip/hip_runtime.h>
#include <hip/hip_bf16.h>
#include <stdint.h>

#define NB 4096
#define NC 100
#define NROWS (NB*NC)        // 409600
#define NTILES (NROWS/64)    // 6400
#define GRID_F 768
#define LH 200
#define LW 50

typedef short v8s __attribute__((ext_vector_type(8)));
typedef float v4f __attribute__((ext_vector_type(4)));
typedef float v2f __attribute__((ext_vector_type(2)));
typedef uint32_t v4u __attribute__((ext_vector_type(4)));

__device__ __forceinline__ v4f mfma16(v8s a, v8s b, v4f c) {
  return __builtin_amdgcn_mfma_f32_16x16x32_bf16(a, b, c, 0, 0, 0);
}

// packed f32x2 -> bf16x2 (lo = first arg), RNE
__device__ __forceinline__ uint32_t pkbf(float lo, float hi) {
  uint32_t r;
  asm("v_cvt_pk_bf16_f32 %0, %1, %2" : "=v"(r) : "v"(lo), "v"(hi));
  return r;
}

__device__ __forceinline__ uint16_t bf16r(float f) {
  uint32_t u = __builtin_bit_cast(uint32_t, f);
  u = (u + 0x7fffu + ((u >> 16) & 1u)) >> 16;
  return (uint16_t)u;
}

__device__ __forceinline__ float bf2f(short s) {
  return __builtin_bit_cast(float, (uint32_t)((uint16_t)s) << 16);
}
__device__ __forceinline__ float flo(uint32_t u) { return __builtin_bit_cast(float, u << 16); }
__device__ __forceinline__ float fhi(uint32_t u) { return __builtin_bit_cast(float, u & 0xffff0000u); }

__device__ __forceinline__ int ntli(const int* p) { return __builtin_nontemporal_load(p); }
__device__ __forceinline__ float ntlf(const float* p) { return __builtin_nontemporal_load(p); }

// barrier that does NOT drain vmcnt: LDS-safe (lgkmcnt), global loads stay in flight
__device__ __forceinline__ void barx() {
  asm volatile("s_waitcnt lgkmcnt(0)" ::: "memory");
  __builtin_amdgcn_s_barrier();
  asm volatile("" ::: "memory");
}

// ---------------- workspace layouts ----------------
// BF16 layout: [0,256K) uv bf16 | [256K,..) frags | [384K, +4.43M) bf16 tables
#define OFF_UVB 0
#define OFF_FW  262144
#define OFF_TB  393216
#define O_EC 0
#define O_EA 640064
#define O_EL 960128
#define O_ET 961920
#define O_EH 3154112
#define O_EW 3794176
#define TB_SZ 4434240
#define WS_NEED (OFF_TB + TB_SZ)
// fallback (f32) layout: [0,512K) uv f32 | [512K,..) frags
#define OFF_UVF32 0
#define OFF_FW32  524288

#define FRAG_B1 0     // 2 frags (even/odd output cols)
#define FRAG_T0 2     // 32 frags: g = wv*8 + ch*4 + ks*2 + p   (k identity)
#define FRAG_T1 34    // 64 frags: g = wv*16 + ch*8 + ks*2 + p  (k PERM32-paired)
#define FRAG_T2 98    // 16 frags: g = wv*4 + ks                (k PERM32-paired)
#define NFRAGS 114

// ---------------- kernel: convert all 6 embedding tables to bf16 ----------------
#define CVT_N 2217120
__global__ void k_cvt(const float* __restrict__ Ec, const float* __restrict__ Ea,
                      const float* __restrict__ El, const float* __restrict__ Et,
                      const float* __restrict__ Eh, const float* __restrict__ Ew,
                      uint16_t* __restrict__ dst) {
  int e = (blockIdx.x * 256 + threadIdx.x) * 4;
  if (e >= CVT_N) return;
  const float* src; int base;
  if (e < 320032)       { src = Ec; base = 0; }
  else if (e < 480064)  { src = Ea; base = 320032; }
  else if (e < 480960)  { src = El; base = 480064; }
  else if (e < 1577056) { src = Et; base = 480960; }
  else if (e < 1897088) { src = Eh; base = 1577056; }
  else                  { src = Ew; base = 1897088; }
  const float* p = src + (e - base);
  float4 v = *(const float4*)p;
  uint32_t a = pkbf(v.x, v.y), b = pkbf(v.z, v.w);
  uint32_t* d = (uint32_t*)(dst + e);
  d[0] = a; d[1] = b;
}

// ---------------- kernel: build weight B-fragments ----------------
__global__ void k_prep(const float* __restrict__ Wb1, const float* __restrict__ Wt0,
                       const float* __restrict__ Wt1, const float* __restrict__ Wt2,
                       uint16_t* __restrict__ fb) {
  int f = blockIdx.x;
  int t = threadIdx.x;
  uint16_t res[2];
  #pragma unroll
  for (int e2 = 0; e2 < 2; ++e2) {
    int e = t * 2 + e2;        // 0..511
    int l = e >> 3, i = e & 7;
    int lr = l & 15, lg = l >> 4;
    float v;
    if (f < FRAG_T0) {                       // Wb1: frag f holds output cols 2*lr+f
      v = Wb1[(lg * 8 + i) * 32 + 2 * lr + f];
    } else if (f < FRAG_T1) {                // Wt0 (k identity)
      int g = f - FRAG_T0;
      int wv = g >> 3, ch = (g >> 2) & 1, ks = (g >> 1) & 1, p = g & 1;
      int n = ch * 128 + wv * 32 + p * 16 + lr;
      int kl = ks * 32 + lg * 8 + i;
      v = Wt0[kl * 256 + n];
    } else if (f < FRAG_T2) {                // Wt1 (act1 pkbf-paired)
      int g = f - FRAG_T1;
      int wv = g >> 4, ch = (g >> 3) & 1, ks = (g >> 1) & 3, p = g & 1;
      int n = wv * 32 + p * 16 + lr;
      int kl = ks * 32 + lg * 8 + i;
      int ok = ch * 128 + (kl & ~31) + ((kl & 31) >> 1) + ((kl & 1) << 4);
      v = Wt1[ok * 128 + n];
    } else {                                 // Wt2 (act2 pkbf-paired)
      int g = f - FRAG_T2;
      int wv = g >> 2, ks = g & 3;
      int n = wv * 16 + lr;
      int kl = ks * 32 + lg * 8 + i;
      int ok = (kl & ~31) + ((kl & 31) >> 1) + ((kl & 1) << 4);
      v = Wt2[ok * 64 + n];
    }
    res[e2] = bf16r(v);
  }
  *(uint32_t*)(fb + (size_t)f * 512 + t * 2) = (uint32_t)res[0] | ((uint32_t)res[1] << 16);
}

// ---------------- user vector: bf16-table variant -> bf16 uv ----------------
__global__ void k_user_bf(const int* __restrict__ hist, const int* __restrict__ wish,
                          const char* __restrict__ tb, uint32_t* __restrict__ uvb) {
  int t = threadIdx.x;
  int d2 = t & 15;
  int r = blockIdx.x * 16 + (t >> 4);
  const uint32_t* Eh32 = (const uint32_t*)(tb + O_EH);
  const uint32_t* Ew32 = (const uint32_t*)(tb + O_EW);
  const int* hr = hist + r * LH;
  float sl = 0.f, sh = 0.f;
  #pragma unroll 8
  for (int j = 0; j < LH; ++j) {
    uint32_t g = Eh32[ntli(hr + j) * 16 + d2];
    sl += flo(g); sh += fhi(g);
  }
  const int* wr = wish + r * LW;
  float wl = 0.f, wh = 0.f;
  #pragma unroll 5
  for (int j = 0; j < LW; ++j) {
    uint32_t g = Ew32[ntli(wr + j) * 16 + d2];
    wl += flo(g); wh += fhi(g);
  }
  uvb[r * 16 + d2] = pkbf(sl * (1.0f/LH) + wl * (1.0f/LW), sh * (1.0f/LH) + wh * (1.0f/LW));
}

// ---------------- user vector: f32 fallback ----------------
__global__ void k_user_f32(const int* __restrict__ hist, const int* __restrict__ wish,
                           const float* __restrict__ Eh, const float* __restrict__ Ew,
                           float* __restrict__ uv) {
  int t = threadIdx.x;
  int d = t & 31;
  int r = (blockIdx.x << 3) + (t >> 5);
  const int* hr = hist + r * LH;
  float s = 0.f;
  #pragma unroll 8
  for (int j = 0; j < LH; ++j) s += Eh[ntli(hr + j) * 32 + d];
  float su = s * (1.0f / LH);
  const int* wr = wish + r * LW;
  s = 0.f;
  #pragma unroll 5
  for (int j = 0; j < LW; ++j) s += Ew[ntli(wr + j) * 32 + d];
  uv[r * 32 + d] = su + s * (1.0f / LW);
}

// ---------------- fused item pipeline ----------------
#define SM_CONST 0       // 672 f32 = 2688 B
#define SM_X     2688    // [64][128B] = 8192
#define SM_ACT3  10880   // [64][128B] = 8192 (H aliased)
#define SM_H     10880   // [64][64B]  = 4096
#define SM_ACT   19072   // [64][256B] = 16384
#define SM_IDX   35456   // 64 rows x 8 idx x 4B = 2048
#define SM_BYTES 37504
// cf: 0 bb1[32] | 32 bt0[256] | 288 bt1[128] | 416 bt2[64] | 480 bb0[32] | 512 Wb0[96] | 608 Wt3[64]

template<int BF>
__global__ __launch_bounds__(256, 3)
void k_fused(const int* __restrict__ cand, const int* __restrict__ auth,
             const int* __restrict__ lang, const int* __restrict__ tags,
             const float* __restrict__ dense,
             const float* __restrict__ Ec, const float* __restrict__ Ea,
             const float* __restrict__ El, const float* __restrict__ Et,
             const char* __restrict__ tb,
             const float* __restrict__ Wb0, const float* __restrict__ bb0,
             const float* __restrict__ bb1, const float* __restrict__ bt0,
             const float* __restrict__ bt1, const float* __restrict__ bt2,
             const float* __restrict__ Wt3, const float* __restrict__ bt3,
             const float* __restrict__ uvec, const uint32_t* __restrict__ uvb,
             const uint16_t* __restrict__ fw, float* __restrict__ out) {
  extern __shared__ char sm[];
  const char* fwp = (const char*)fw;
  float* cf = (float*)(sm + SM_CONST);
  const int t = threadIdx.x;
  const int l = t & 63, wv = t >> 6;
  const int lr = l & 15, lg = l >> 4;
  const int q = t & 3, rowl = t >> 2;

  // ---- stage constants ----
  cf[32 + t] = bt0[t];
  if (t < 128) cf[288 + t] = bt1[t];
  if (t < 64)  { cf[416 + t] = bt2[t]; cf[608 + t] = Wt3[t]; }
  if (t < 32)  { cf[t] = bb1[t]; cf[480 + t] = bb0[t]; }
  if (t < 96)  cf[512 + t] = Wb0[t];
  const float bt3v = bt3[0];

  // ---- prefetch state (one tile lookahead) ----
  v4u u4;
  float4 uf0, uf1;
  float d3x, d3y, d3z;
  int i2a, i2b;

  auto ld_tile = [&](int tl) {
    int rr0 = (tl << 6) + rowl;
    int b = rr0 / 100;
    if constexpr (BF) {
      u4 = *(const v4u*)(uvb + b * 16 + q * 4);
    } else {
      uf0 = *(const float4*)(uvec + b * 32 + q * 8);
      uf1 = *(const float4*)(uvec + b * 32 + q * 8 + 4);
    }
    d3x = ntlf(dense + rr0 * 3 + 0);
    d3y = ntlf(dense + rr0 * 3 + 1);
    d3z = ntlf(dense + rr0 * 3 + 2);
    int s0 = q * 2;
    i2a = (s0 == 0) ? ntli(cand + rr0) : (s0 == 2) ? ntli(lang + rr0)
        : (s0 == 4) ? ntli(tags + rr0 * 5 + 1) : ntli(tags + rr0 * 5 + 3);
    i2b = (s0 == 0) ? ntli(auth + rr0) : (s0 == 2) ? ntli(tags + rr0 * 5 + 0)
        : (s0 == 4) ? ntli(tags + rr0 * 5 + 2) : ntli(tags + rr0 * 5 + 4);
  };

  ld_tile(blockIdx.x);

  for (int tile = blockIdx.x; tile < NTILES; tile += GRID_F) {
    const int r0 = tile << 6;
    barx();   // protects X/ACT3/H/IDX reuse across tiles (and staging, tile 0)

    // ---- P0: X u-part + idx->LDS + bottom-MLP layer0 (h) ----
    {
      int xrb = SM_X + rowl * 128;
      int sw  = (rowl & 7) << 4;
      if constexpr (BF) {
        #pragma unroll
        for (int k2 = 0; k2 < 4; ++k2)
          *(uint32_t*)(sm + xrb + ((q * 16 + k2 * 4) ^ sw)) = u4[k2];
      } else {
        float uu[8] = {uf0.x, uf0.y, uf0.z, uf0.w, uf1.x, uf1.y, uf1.z, uf1.w};
        #pragma unroll
        for (int k2 = 0; k2 < 4; ++k2)
          *(uint32_t*)(sm + xrb + ((q * 16 + k2 * 4) ^ sw)) = pkbf(uu[2*k2], uu[2*k2+1]);
      }
      *(int*)(sm + SM_IDX + rowl * 32 + q * 8)     = i2a;
      *(int*)(sm + SM_IDX + rowl * 32 + q * 8 + 4) = i2b;
      const float* bb0l = cf + 480;
      const float* w0a = cf + 512, *w0b = cf + 544, *w0c = cf + 576;
      int hrb = SM_H + rowl * 64;
      int sw3 = (rowl & 3) << 4;
      #pragma unroll
      for (int u2 = 0; u2 < 4; ++u2) {
        int e0 = q * 8 + u2 * 2, e1 = e0 + 1;
        float h0 = fmaxf(bb0l[e0] + d3x * w0a[e0] + d3y * w0b[e0] + d3z * w0c[e0], 0.f);
        float h1 = fmaxf(bb0l[e1] + d3x * w0a[e1] + d3y * w0b[e1] + d3z * w0c[e1], 0.f);
        *(uint32_t*)(sm + hrb + ((q * 16 + u2 * 4) ^ sw3)) = pkbf(h0, h1);
      }
    }
    barx();

    // issue next tile's stream loads NOW — they stay in flight across barx()
    if (tile + GRID_F < NTILES) ld_tile(tile + GRID_F);

    // ---- P1: b1 MFMA (d_vec) + gathers (idx from LDS) -> X i-part ----
    {
      int hrow = 16 * wv + lr;
      v8s ah  = *(const v8s*)(sm + SM_H + hrow * 64 + ((lg * 16) ^ ((hrow & 3) << 4)));
      v8s wbl = *(const v8s*)(fwp + (size_t)(FRAG_B1 + 0) * 1024 + l * 16);
      v8s wbh = *(const v8s*)(fwp + (size_t)(FRAG_B1 + 1) * 1024 + l * 16);
      float b0v = cf[2 * lr], b1v = cf[2 * lr + 1];
      v4f dv0 = {b0v, b0v, b0v, b0v};
      v4f dv1 = {b1v, b1v, b1v, b1v};
      dv0 = mfma16(ah, wbl, dv0);   // i dims 2*lr
      dv1 = mfma16(ah, wbh, dv1);   // i dims 2*lr+1
      #pragma unroll
      for (int j = 0; j < 4; ++j) {
        int mrow = 16 * wv + lg * 4 + j;
        const int* ip = (const int*)(sm + SM_IDX + mrow * 32);
        int ic = ip[0], ia = ip[1], il = ip[2];
        int t0i = ip[3], t1i = ip[4], t2i = ip[5], t3i = ip[6], t4i = ip[7];
        float s0, s1;
        if constexpr (BF) {
          uint32_t gc = *(const uint32_t*)(tb + O_EC + (size_t)ic * 64 + lr * 4);
          uint32_t ga = *(const uint32_t*)(tb + O_EA + (size_t)ia * 64 + lr * 4);
          uint32_t gl = *(const uint32_t*)(tb + O_EL + (size_t)il * 64 + lr * 4);
          uint32_t g0 = *(const uint32_t*)(tb + O_ET + (size_t)t0i * 64 + lr * 4);
          uint32_t g1 = *(const uint32_t*)(tb + O_ET + (size_t)t1i * 64 + lr * 4);
          uint32_t g2 = *(const uint32_t*)(tb + O_ET + (size_t)t2i * 64 + lr * 4);
          uint32_t g3 = *(const uint32_t*)(tb + O_ET + (size_t)t3i * 64 + lr * 4);
          uint32_t g4 = *(const uint32_t*)(tb + O_ET + (size_t)t4i * 64 + lr * 4);
          s0 = flo(gc) + flo(ga) + flo(gl)
             + (flo(g0) + flo(g1) + flo(g2) + flo(g3) + flo(g4)) * 0.2f + dv0[j];
          s1 = fhi(gc) + fhi(ga) + fhi(gl)
             + (fhi(g0) + fhi(g1) + fhi(g2) + fhi(g3) + fhi(g4)) * 0.2f + dv1[j];
        } else {
          int co = 2 * lr;
          v2f ec = *(const v2f*)(Ec + ic * 32 + co);
          v2f ea = *(const v2f*)(Ea + ia * 32 + co);
          v2f el = *(const v2f*)(El + il * 32 + co);
          v2f e0 = *(const v2f*)(Et + t0i * 32 + co);
          v2f e1 = *(const v2f*)(Et + t1i * 32 + co);
          v2f e2 = *(const v2f*)(Et + t2i * 32 + co);
          v2f e3 = *(const v2f*)(Et + t3i * 32 + co);
          v2f e4 = *(const v2f*)(Et + t4i * 32 + co);
          s0 = ec[0] + ea[0] + el[0] + (e0[0]+e1[0]+e2[0]+e3[0]+e4[0]) * 0.2f + dv0[j];
          s1 = ec[1] + ea[1] + el[1] + (e0[1]+e1[1]+e2[1]+e3[1]+e4[1]) * 0.2f + dv1[j];
        }
        *(uint32_t*)(sm + SM_X + mrow * 128 + ((64 + 4 * lr) ^ ((mrow & 7) << 4))) = pkbf(s0, s1);
      }
    }
    barx();

    // ---- t0 (64->256) + t1 (256->128) in two 128-col chunks ----
    v4f acc2[2][4];
    #pragma unroll
    for (int ch = 0; ch < 2; ++ch) {
      v4f a1[2][4];
      #pragma unroll
      for (int p = 0; p < 2; ++p) {
        float bv = cf[32 + ch * 128 + wv * 32 + p * 16 + lr];
        #pragma unroll
        for (int m = 0; m < 4; ++m) a1[p][m] = (v4f){bv, bv, bv, bv};
      }
      #pragma unroll
      for (int ks = 0; ks < 2; ++ks) {
        v8s xa[4];
        #pragma unroll
        for (int m = 0; m < 4; ++m)
          xa[m] = *(const v8s*)(sm + SM_X + (m * 16 + lr) * 128 + ((ks * 64 + lg * 16) ^ ((lr & 7) << 4)));
        #pragma unroll
        for (int p = 0; p < 2; ++p) {
          v8s wb = *(const v8s*)(fwp + (size_t)(FRAG_T0 + wv * 8 + ch * 4 + ks * 2 + p) * 1024 + l * 16);
          #pragma unroll
          for (int m = 0; m < 4; ++m) a1[p][m] = mfma16(xa[m], wb, a1[p][m]);
        }
      }
      #pragma unroll
      for (int m = 0; m < 4; ++m) {
        #pragma unroll
        for (int j = 0; j < 4; ++j) {
          int row = m * 16 + lg * 4 + j;
          *(uint32_t*)(sm + SM_ACT + row * 256 + ((wv * 64 + 4 * lr) ^ ((row & 7) << 4)))
            = pkbf(fmaxf(a1[0][m][j], 0.f), fmaxf(a1[1][m][j], 0.f));
        }
      }
      barx();
      if (ch == 0) {
        #pragma unroll
        for (int p = 0; p < 2; ++p) {
          float bv = cf[288 + wv * 32 + p * 16 + lr];
          #pragma unroll
          for (int m = 0; m < 4; ++m) acc2[p][m] = (v4f){bv, bv, bv, bv};
        }
      }
      #pragma unroll
      for (int ks = 0; ks < 4; ++ks) {
        v8s aa[4];
        #pragma unroll
        for (int m = 0; m < 4; ++m)
          aa[m] = *(const v8s*)(sm + SM_ACT + (m * 16 + lr) * 256 + ((ks * 64 + lg * 16) ^ ((lr & 7) << 4)));
        #pragma unroll
        for (int p = 0; p < 2; ++p) {
          v8s wb = *(const v8s*)(fwp + (size_t)(FRAG_T1 + wv * 16 + ch * 8 + ks * 2 + p) * 1024 + l * 16);
          #pragma unroll
          for (int m = 0; m < 4; ++m) acc2[p][m] = mfma16(aa[m], wb, acc2[p][m]);
        }
      }
      barx();
    }
    // act2 (relu, paired)
    #pragma unroll
    for (int m = 0; m < 4; ++m) {
      #pragma unroll
      for (int j = 0; j < 4; ++j) {
        int row = m * 16 + lg * 4 + j;
        *(uint32_t*)(sm + SM_ACT + row * 256 + ((wv * 64 + 4 * lr) ^ ((row & 7) << 4)))
          = pkbf(fmaxf(acc2[0][m][j], 0.f), fmaxf(acc2[1][m][j], 0.f));
      }
    }
    barx();

    // ---- t2 (128->64) ----
    {
      int n2 = wv * 16 + lr;
      float bv = cf[416 + n2];
      v4f a3[4];
      #pragma unroll
      for (int m = 0; m < 4; ++m) a3[m] = (v4f){bv, bv, bv, bv};
      #pragma unroll
      for (int ks = 0; ks < 4; ++ks) {
        v8s wb = *(const v8s*)(fwp + (size_t)(FRAG_T2 + wv * 4 + ks) * 1024 + l * 16);
        #pragma unroll
        for (int m = 0; m < 4; ++m) {
          v8s aa = *(const v8s*)(sm + SM_ACT + (m * 16 + lr) * 256 + ((ks * 64 + lg * 16) ^ ((lr & 7) << 4)));
          a3[m] = mfma16(aa, wb, a3[m]);
        }
      }
      #pragma unroll
      for (int m = 0; m < 4; ++m) {
        #pragma unroll
        for (int j = 0; j < 4; ++j) {
          int row = m * 16 + lg * 4 + j;
          *(uint16_t*)(sm + SM_ACT3 + row * 128 + ((2 * n2) ^ ((row & 7) << 4))) = bf16r(fmaxf(a3[m][j], 0.f));
        }
      }
    }
    barx();

    // ---- t3 (64->1) ----
    {
      float acc = 0.f;
      int arb = SM_ACT3 + rowl * 128;
      int sw  = (rowl & 7) << 4;
      const float* wt3l = cf + 608;
      #pragma unroll
      for (int hf = 0; hf < 2; ++hf) {
        v8s av = *(const v8s*)(sm + arb + ((q * 32 + hf * 16) ^ sw));
        #pragma unroll
        for (int i = 0; i < 8; ++i) acc += bf2f(av[i]) * wt3l[q * 16 + hf * 8 + i];
      }
      acc += __shfl_xor(acc, 1);
      acc += __shfl_xor(acc, 2);
      if (q == 0) out[r0 + rowl] = acc + bt3v;
    }
  }
}

extern "C" void kernel_launch(void* const* d_in, const int* in_sizes, int n_in,
                              void* d_out, int out_size, void* d_ws, size_t ws_size,
                              hipStream_t stream) {
  const int*   hist  = (const int*)d_in[0];
  const int*   wish  = (const int*)d_in[1];
  const int*   cand  = (const int*)d_in[2];
  const int*   auth  = (const int*)d_in[3];
  const int*   lang  = (const int*)d_in[4];
  const int*   tags  = (const int*)d_in[5];
  const float* dense = (const float*)d_in[6];
  const float* Eh    = (const float*)d_in[7];
  const float* Ew    = (const float*)d_in[8];
  const float* Ec    = (const float*)d_in[9];
  const float* Ea    = (const float*)d_in[10];
  const float* El    = (const float*)d_in[11];
  const float* Et    = (const float*)d_in[12];
  const float* Wb0   = (const float*)d_in[13];
  const float* bb0   = (const float*)d_in[14];
  const float* Wb1   = (const float*)d_in[15];
  const float* bb1   = (const float*)d_in[16];
  const float* Wt0   = (const float*)d_in[17];
  const float* bt0   = (const float*)d_in[18];
  const float* Wt1   = (const float*)d_in[19];
  const float* bt1   = (const float*)d_in[20];
  const float* Wt2   = (const float*)d_in[21];
  const float* bt2   = (const float*)d_in[22];
  const float* Wt3   = (const float*)d_in[23];
  const float* bt3   = (const float*)d_in[24];
  char* wsb = (char*)d_ws;
  float* out = (float*)d_out;

  if (ws_size >= (size_t)WS_NEED) {
    uint32_t* uvb = (uint32_t*)(wsb + OFF_UVB);
    uint16_t* fw  = (uint16_t*)(wsb + OFF_FW);
    char*     tb  = wsb + OFF_TB;
    auto kf = k_fused<1>;
    (void)hipFuncSetAttribute((const void*)kf,
                              hipFuncAttributeMaxDynamicSharedMemorySize, SM_BYTES);
    k_cvt<<<(CVT_N / 4 + 255) / 256, 256, 0, stream>>>(Ec, Ea, El, Et, Eh, Ew, (uint16_t*)tb);
    k_prep<<<NFRAGS, 256, 0, stream>>>(Wb1, Wt0, Wt1, Wt2, fw);
    k_user_bf<<<NB / 16, 256, 0, stream>>>(hist, wish, tb, uvb);
    kf<<<GRID_F, 256, SM_BYTES, stream>>>(cand, auth, lang, tags, dense,
        Ec, Ea, El, Et, tb, Wb0, bb0, bb1, bt0, bt1, bt2, Wt3, bt3,
        (const float*)nullptr, uvb, fw, out);
  } else {
    float*    uv = (float*)(wsb + OFF_UVF32);
    uint16_t* fw = (uint16_t*)(wsb + OFF_FW32);
    auto kf = k_fused<0>;
    (void)hipFuncSetAttribute((const void*)kf,
                              hipFuncAttributeMaxDynamicSharedMemorySize, SM_BYTES);
    k_prep<<<NFRAGS, 256, 0, stream>>>(Wb1, Wt0, Wt1, Wt2, fw);
    k_user_f32<<<NB / 8, 256, 0, stream>>>(hist, wish, Eh, Ew, uv);
    kf<<<GRID_F, 256, SM_BYTES, stream>>>(cand, auth, lang, tags, dense,
        Ec, Ea, El, Et, (const char*)nullptr, Wb0, bb0, bb1, bt0, bt1, bt2, Wt3, bt3,
        uv, (const uint32_t*)nullptr, fw, out);
  }
}